// Round 1
// baseline (368.599 us; speedup 1.0000x reference)
//
#include <hip/hip_runtime.h>
#include <hip/hip_bf16.h>

typedef __attribute__((ext_vector_type(4))) float f32x4;
typedef __attribute__((ext_vector_type(8))) short bf16x8;

#define NEG_L2K (-0.025952563241307517f)  // -log2(10000)/512

__device__ __forceinline__ unsigned short f2bf(float f) {
    union { float f; unsigned int u; } v; v.f = f;
    unsigned int r = v.u + 0x7FFFu + ((v.u >> 16) & 1u);
    return (unsigned short)(r >> 16);
}

// ---------------- Kernel 1: X fp32 -> bf16 (same layout); zero A[8192] ----
__global__ void prep_x_kernel(const float* __restrict__ X,
                              unsigned short* __restrict__ Xb,
                              float* __restrict__ A, int n8) {
    int gid = blockIdx.x * blockDim.x + threadIdx.x;
    if (gid < 8192) A[gid] = 0.0f;
    int stride = gridDim.x * blockDim.x;
    for (int i = gid; i < n8; i += stride) {
        float4 a = ((const float4*)X)[2 * i];
        float4 b = ((const float4*)X)[2 * i + 1];
        union { unsigned short us[8]; uint4 v; } o;
        o.us[0] = f2bf(a.x); o.us[1] = f2bf(a.y);
        o.us[2] = f2bf(a.z); o.us[3] = f2bf(a.w);
        o.us[4] = f2bf(b.x); o.us[5] = f2bf(b.y);
        o.us[6] = f2bf(b.z); o.us[7] = f2bf(b.w);
        ((uint4*)Xb)[i] = o.v;
    }
}

// ---------------- Kernel 2: W [2048][4096] fp32 -> Wt [4096][2048] bf16 ---
__global__ __launch_bounds__(256) void prep_w_kernel(const float* __restrict__ W,
                                                     unsigned short* __restrict__ Wt) {
    __shared__ unsigned short t[64][65];
    int f0 = blockIdx.x * 64;   // along 4096
    int k0 = blockIdx.y * 64;   // along 2048
    int tx = threadIdx.x & 63;
    int ty = threadIdx.x >> 6;  // 0..3
    for (int j = 0; j < 64; j += 4)
        t[ty + j][tx] = f2bf(W[(size_t)(k0 + ty + j) * 4096 + f0 + tx]);
    __syncthreads();
    for (int j = 0; j < 64; j += 4)
        Wt[(size_t)(f0 + ty + j) * 2048 + k0 + tx] = t[tx][ty + j];
}

// ---------------- Kernel 3: fused GEMM + rotary + cos*cos + col-reduce ----
// Block: 256 thr (4 waves, 2x2). Tile: 128 rows x 128 K-cols (+ paired V-cols).
__global__ __launch_bounds__(256, 2) void gemm_acos_kernel(
    const unsigned short* __restrict__ Xb,   // [16384][2048]
    const unsigned short* __restrict__ Wt,   // [4096][2048]
    const float* __restrict__ bias,          // [4096]
    float* __restrict__ A)                   // [4][2048]
{
    __shared__ __align__(16) unsigned short As[128 * 64];
    __shared__ __align__(16) unsigned short BsK[128 * 64];
    __shared__ __align__(16) unsigned short BsV[128 * 64];

    const int tid  = threadIdx.x;
    const int lane = tid & 63;
    const int wid  = tid >> 6;
    const int wr   = wid >> 1;   // 0..1
    const int wc   = wid & 1;    // 0..1

    const int row0 = blockIdx.y * 128;   // 0..16256
    const int n0   = blockIdx.x * 128;   // 0..1920

    f32x4 accK[4][4] = {};
    f32x4 accV[4][4] = {};

    const unsigned short* gA  = Xb + (size_t)row0 * 2048;
    const unsigned short* gBK = Wt + (size_t)n0 * 2048;
    const unsigned short* gBV = Wt + (size_t)(n0 + 2048) * 2048;

    const int lr = lane & 15;
    const int lk = (lane >> 4) * 8;

    for (int kt = 0; kt < 2048; kt += 64) {
        // ---- stage 3 tiles via global_load_lds (16B/lane, 4 issues each)
        #pragma unroll
        for (int j = 0; j < 4; ++j) {
            int c  = j * 256 + tid;       // 16B-chunk id, 8 chunks/row
            int r  = c >> 3;
            int co = (c & 7) * 8;
            __builtin_amdgcn_global_load_lds(
                (const __attribute__((address_space(1))) void*)(gA + (size_t)r * 2048 + kt + co),
                (__attribute__((address_space(3))) void*)(As + c * 8), 16, 0, 0);
            __builtin_amdgcn_global_load_lds(
                (const __attribute__((address_space(1))) void*)(gBK + (size_t)r * 2048 + kt + co),
                (__attribute__((address_space(3))) void*)(BsK + c * 8), 16, 0, 0);
            __builtin_amdgcn_global_load_lds(
                (const __attribute__((address_space(1))) void*)(gBV + (size_t)r * 2048 + kt + co),
                (__attribute__((address_space(3))) void*)(BsV + c * 8), 16, 0, 0);
        }
        __syncthreads();

        #pragma unroll
        for (int ks = 0; ks < 2; ++ks) {
            bf16x8 af[4], bk[4], bv[4];
            #pragma unroll
            for (int m = 0; m < 4; ++m)
                af[m] = *(const bf16x8*)&As[(wr * 64 + m * 16 + lr) * 64 + ks * 32 + lk];
            #pragma unroll
            for (int n = 0; n < 4; ++n) {
                bk[n] = *(const bf16x8*)&BsK[(wc * 64 + n * 16 + lr) * 64 + ks * 32 + lk];
                bv[n] = *(const bf16x8*)&BsV[(wc * 64 + n * 16 + lr) * 64 + ks * 32 + lk];
            }
            #pragma unroll
            for (int m = 0; m < 4; ++m)
                #pragma unroll
                for (int n = 0; n < 4; ++n) {
                    accK[m][n] = __builtin_amdgcn_mfma_f32_16x16x32_bf16(af[m], bk[n], accK[m][n], 0, 0, 0);
                    accV[m][n] = __builtin_amdgcn_mfma_f32_16x16x32_bf16(af[m], bv[n], accV[m][n], 0, 0, 0);
                }
        }
        __syncthreads();
    }

    // ---- epilogue: bias, rotary, cos*cos, reduce over rows, atomicAdd
    const int batch = row0 >> 12;                       // /4096 (128 | 4096)
    const int sbase = (row0 & 4095) + wr * 64 + ((lane >> 4) * 4);

    #pragma unroll
    for (int n = 0; n < 4; ++n) {
        const int c     = n0 + wc * 64 + n * 16 + lr;   // channel in [0,2048)
        const float bK  = bias[c];
        const float bV  = bias[c + 2048];
        const bool rot  = (c < 1024);                   // uniform per fragment
        const float invf = exp2f((float)(c >> 1) * NEG_L2K);
        const float sgn  = (c & 1) ? 1.0f : -1.0f;
        float colsum = 0.0f;
        #pragma unroll
        for (int m = 0; m < 4; ++m) {
            const int srow = sbase + m * 16;
            #pragma unroll
            for (int q = 0; q < 4; ++q) {
                float kv = accK[m][n][q] + bK;
                float vv = accV[m][n][q] + bV;
                float pk = __shfl_xor(kv, 1);
                float pv = __shfl_xor(vv, 1);
                float krot = kv, vrot = vv;
                if (rot) {
                    float sn, cs;
                    __sincosf((float)(srow + q) * invf, &sn, &cs);
                    float t = sgn * sn;
                    krot = kv * cs + pk * t;
                    vrot = vv * cs + pv * t;
                }
                colsum += __cosf(krot) * __cosf(vrot);
            }
        }
        colsum += __shfl_xor(colsum, 16);
        colsum += __shfl_xor(colsum, 32);
        if (lane < 16)
            atomicAdd(&A[batch * 2048 + c], colsum);
    }
}

// ---------------- Kernel 4: out = (0.5*A + 0.5) * X --------------------
__global__ void scale_out_kernel(const float* __restrict__ X,
                                 const float* __restrict__ A,
                                 float* __restrict__ out, int n4) {
    int gid = blockIdx.x * blockDim.x + threadIdx.x;
    int stride = gridDim.x * blockDim.x;
    for (int i = gid; i < n4; i += stride) {
        int e0 = i * 4;
        int b  = e0 >> 23;        // S*D = 2^23
        int d  = e0 & 2047;
        float4 a4 = *(const float4*)(A + b * 2048 + d);
        float4 x4 = ((const float4*)X)[i];
        float4 o;
        o.x = (0.5f * a4.x + 0.5f) * x4.x;
        o.y = (0.5f * a4.y + 0.5f) * x4.y;
        o.z = (0.5f * a4.z + 0.5f) * x4.z;
        o.w = (0.5f * a4.w + 0.5f) * x4.w;
        ((float4*)out)[i] = o;
    }
}

extern "C" void kernel_launch(void* const* d_in, const int* in_sizes, int n_in,
                              void* d_out, int out_size, void* d_ws, size_t ws_size,
                              hipStream_t stream) {
    const float* X    = (const float*)d_in[0];   // [4][4096][2048]
    const float* W    = (const float*)d_in[1];   // [2048][4096]
    const float* bias = (const float*)d_in[2];   // [4096]
    float* out = (float*)d_out;

    const size_t szA  = 32768;                       // 4*2048*4 (padded)
    const size_t szWt = (size_t)4096 * 2048 * 2;     // 16.8 MB
    const size_t szXb = (size_t)16384 * 2048 * 2;    // 67.1 MB

    char* ws = (char*)d_ws;
    float* A = (float*)ws;                           // assume ws >= 32 KB
    unsigned short* Wt;
    unsigned short* Xb;
    if (ws_size >= szA + szWt + szXb) {
        Wt = (unsigned short*)(ws + szA);
        Xb = (unsigned short*)(ws + szA + szWt);
    } else if (ws_size >= szA + szWt) {
        Wt = (unsigned short*)(ws + szA);
        Xb = (unsigned short*)d_out;                 // scratch; rewritten by kernel 4
    } else {
        Xb = (unsigned short*)d_out;
        Wt = (unsigned short*)((char*)d_out + szXb); // 67+16.8 MB <= 134 MB
    }

    prep_x_kernel<<<2048, 256, 0, stream>>>(X, Xb, A, 16384 * 2048 / 8);
    prep_w_kernel<<<dim3(64, 32), 256, 0, stream>>>(W, Wt);
    gemm_acos_kernel<<<dim3(16, 128), 256, 0, stream>>>(Xb, Wt, bias, A);
    scale_out_kernel<<<2048, 256, 0, stream>>>(X, A, out, 16384 * 2048 / 4);
}

// Round 2
// 343.497 us; speedup vs baseline: 1.0731x; 1.0731x over previous
//
#include <hip/hip_runtime.h>
#include <hip/hip_bf16.h>

typedef __attribute__((ext_vector_type(4))) float f32x4;
typedef __attribute__((ext_vector_type(8))) short bf16x8;

#define NEG_L2K (-0.025952563241307517f)  // -log2(10000)/512

#define VMW(N) asm volatile("s_waitcnt vmcnt(" #N ")" ::: "memory")
#define SBAR() __builtin_amdgcn_s_barrier()

__device__ __forceinline__ unsigned short f2bf(float f) {
    union { float f; unsigned int u; } v; v.f = f;
    unsigned int r = v.u + 0x7FFFu + ((v.u >> 16) & 1u);
    return (unsigned short)(r >> 16);
}

__device__ __forceinline__ f32x4 MFMA(bf16x8 a, bf16x8 b, f32x4 c) {
    return __builtin_amdgcn_mfma_f32_16x16x32_bf16(a, b, c, 0, 0, 0);
}

// ---------------- Kernel 1: X fp32 -> bf16 (same layout); zero A[8192] ----
__global__ void prep_x_kernel(const float* __restrict__ X,
                              unsigned short* __restrict__ Xb,
                              float* __restrict__ A, int n8) {
    int gid = blockIdx.x * blockDim.x + threadIdx.x;
    if (gid < 8192) A[gid] = 0.0f;
    int stride = gridDim.x * blockDim.x;
    for (int i = gid; i < n8; i += stride) {
        float4 a = ((const float4*)X)[2 * i];
        float4 b = ((const float4*)X)[2 * i + 1];
        union { unsigned short us[8]; uint4 v; } o;
        o.us[0] = f2bf(a.x); o.us[1] = f2bf(a.y);
        o.us[2] = f2bf(a.z); o.us[3] = f2bf(a.w);
        o.us[4] = f2bf(b.x); o.us[5] = f2bf(b.y);
        o.us[6] = f2bf(b.z); o.us[7] = f2bf(b.w);
        ((uint4*)Xb)[i] = o.v;
    }
}

// ---------------- Kernel 2: W [2048][4096] fp32 -> Wt [4096][2048] bf16 ---
__global__ __launch_bounds__(256) void prep_w_kernel(const float* __restrict__ W,
                                                     unsigned short* __restrict__ Wt) {
    __shared__ unsigned short t[64][65];
    int f0 = blockIdx.x * 64;   // along 4096
    int k0 = blockIdx.y * 64;   // along 2048
    int tx = threadIdx.x & 63;
    int ty = threadIdx.x >> 6;  // 0..3
    for (int j = 0; j < 64; j += 4)
        t[ty + j][tx] = f2bf(W[(size_t)(k0 + ty + j) * 4096 + f0 + tx]);
    __syncthreads();
    for (int j = 0; j < 64; j += 4)
        Wt[(size_t)(f0 + ty + j) * 2048 + k0 + tx] = t[tx][ty + j];
}

// ---- staging helper: one 128-row x 64-col bf16 tile (16 KB), 2 loads/thread
// LDS dest linear; global source pre-swizzled (chunk jl = jp ^ (row&7)) so that
// swizzled ds_reads (T2) see the right data.  Per wave-instruction: 64 lanes
// cover 8 consecutive rows contiguously (coalesced 1 KB).
__device__ __forceinline__ void stage128(const unsigned short* __restrict__ g,
                                         unsigned short* lds, int tid) {
    int lane = tid & 63, w = tid >> 6;
    #pragma unroll
    for (int q = 0; q < 2; ++q) {
        int c = (q * 8 + w) * 64 + lane;          // physical 16B-chunk id
        int row = c >> 3;
        int jl = (c & 7) ^ (row & 7);             // logical chunk in row
        __builtin_amdgcn_global_load_lds(
            (const __attribute__((address_space(1))) void*)(g + (size_t)row * 2048 + jl * 8),
            (__attribute__((address_space(3))) void*)(lds + c * 8), 16, 0, 0);
    }
}

// ---------------- Kernel 3: fused GEMM + rotary + cos*cos + col-reduce ----
// 8-phase-class schedule: BM=256, BN=128 (+paired V cols), BK=64, 8 waves,
// dbuf LDS 128 KiB, counted vmcnt, T2 swizzle, T5 setprio, T1 XCD swizzle.
__global__ __launch_bounds__(512, 2) void gemm_acos_kernel(
    const unsigned short* __restrict__ Xb,   // [16384][2048]
    const unsigned short* __restrict__ Wt,   // [4096][2048]
    const float* __restrict__ bias,          // [4096]
    float* __restrict__ A)                   // [4][2048]
{
    __shared__ __align__(16) unsigned short Als[2][256 * 64];  // 64 KB
    __shared__ __align__(16) unsigned short Kls[2][128 * 64];  // 32 KB
    __shared__ __align__(16) unsigned short Vls[2][128 * 64];  // 32 KB

    const int tid  = threadIdx.x;
    const int lane = tid & 63;
    const int wid  = tid >> 6;    // 0..7
    const int wr   = wid >> 2;    // 0..1  (row half)
    const int wc   = wid & 3;     // 0..3  (col quarter: 32 cols)
    const int lr   = lane & 15;
    const int hi   = lane >> 4;   // 0..3
    const int e    = lane & 7;

    // T1: bijective XCD swizzle, grid 1024 = 64 mtiles x 16 ntiles, ntile-major
    const int orig  = blockIdx.x;
    const int wg    = (orig & 7) * 128 + (orig >> 3);
    const int mtile = wg & 63;
    const int ntile = wg >> 6;
    const int row0  = mtile * 256;
    const int n0    = ntile * 128;

    const unsigned short* gA = Xb + (size_t)row0 * 2048;
    const unsigned short* gK = Wt + (size_t)n0 * 2048;
    const unsigned short* gV = Wt + (size_t)(n0 + 2048) * 2048;

    f32x4 accK[8][2] = {};
    f32x4 accV[8][2] = {};

    // ds_read byte offsets (T2-swizzled chunk: (ks*4+hi) ^ (lane&7))
    const int aoff = (wr * 128 + lr) * 128;
    const int boff = (wc * 32 + lr) * 128;
    const int x0   = ((0 + hi) ^ e) * 16;
    const int x1   = ((4 + hi) ^ e) * 16;

    // prologue: stage tile 0 into buf 0 (issue order = A-lo, A-hi, K, V)
    stage128(gA,                Als[0],            tid);
    stage128(gA + 128 * 2048,   Als[0] + 128 * 64, tid);
    stage128(gK,                Kls[0],            tid);
    stage128(gV,                Vls[0],            tid);

    int cur = 0;
    for (int kt = 0; kt < 2048; kt += 64) {
        const bool last = (kt == 2048 - 64);
        const unsigned short* As = Als[cur];
        const unsigned short* Ks = Kls[cur];
        const unsigned short* Vs = Vls[cur];
        unsigned short* An = Als[cur ^ 1];
        unsigned short* Kn = Kls[cur ^ 1];
        unsigned short* Vn = Vls[cur ^ 1];
        const int ktn = kt + 64;

        bf16x8 af0[4][2], af1[4][2], bk[2][2], bv[2][2];

        // ---- P0: need A(both halves)+BK of tile t done; BV may fly
        VMW(2);
        SBAR();
        #pragma unroll
        for (int m = 0; m < 4; ++m) {
            af0[m][0] = *(const bf16x8*)((const char*)As + aoff + m * 2048 + x0);
            af0[m][1] = *(const bf16x8*)((const char*)As + aoff + m * 2048 + x1);
        }
        #pragma unroll
        for (int n = 0; n < 2; ++n) {
            bk[n][0] = *(const bf16x8*)((const char*)Ks + boff + n * 2048 + x0);
            bk[n][1] = *(const bf16x8*)((const char*)Ks + boff + n * 2048 + x1);
        }
        if (!last) stage128(gA + ktn, An, tid);
        SBAR();
        __builtin_amdgcn_s_setprio(1);
        #pragma unroll
        for (int m = 0; m < 4; ++m)
            #pragma unroll
            for (int n = 0; n < 2; ++n) {
                accK[m][n] = MFMA(af0[m][0], bk[n][0], accK[m][n]);
                accK[m][n] = MFMA(af0[m][1], bk[n][1], accK[m][n]);
            }
        __builtin_amdgcn_s_setprio(0);

        // ---- P1: need BV of tile t done
        if (!last) { VMW(2); } else { VMW(0); }
        SBAR();
        #pragma unroll
        for (int n = 0; n < 2; ++n) {
            bv[n][0] = *(const bf16x8*)((const char*)Vs + boff + n * 2048 + x0);
            bv[n][1] = *(const bf16x8*)((const char*)Vs + boff + n * 2048 + x1);
        }
        if (!last) stage128(gA + 128 * 2048 + ktn, An + 128 * 64, tid);
        SBAR();
        __builtin_amdgcn_s_setprio(1);
        #pragma unroll
        for (int m = 0; m < 4; ++m)
            #pragma unroll
            for (int n = 0; n < 2; ++n) {
                accV[m][n] = MFMA(af0[m][0], bv[n][0], accV[m][n]);
                accV[m][n] = MFMA(af0[m][1], bv[n][1], accV[m][n]);
            }
        __builtin_amdgcn_s_setprio(0);

        // ---- P2: K-part rows m4-7
        SBAR();
        #pragma unroll
        for (int m = 0; m < 4; ++m) {
            af1[m][0] = *(const bf16x8*)((const char*)As + aoff + (m + 4) * 2048 + x0);
            af1[m][1] = *(const bf16x8*)((const char*)As + aoff + (m + 4) * 2048 + x1);
        }
        if (!last) stage128(gK + ktn, Kn, tid);
        SBAR();
        __builtin_amdgcn_s_setprio(1);
        #pragma unroll
        for (int m = 0; m < 4; ++m)
            #pragma unroll
            for (int n = 0; n < 2; ++n) {
                accK[m + 4][n] = MFMA(af1[m][0], bk[n][0], accK[m + 4][n]);
                accK[m + 4][n] = MFMA(af1[m][1], bk[n][1], accK[m + 4][n]);
            }
        __builtin_amdgcn_s_setprio(0);

        // ---- P3: V-part rows m4-7
        SBAR();
        if (!last) stage128(gV + ktn, Vn, tid);
        SBAR();
        __builtin_amdgcn_s_setprio(1);
        #pragma unroll
        for (int m = 0; m < 4; ++m)
            #pragma unroll
            for (int n = 0; n < 2; ++n) {
                accV[m + 4][n] = MFMA(af1[m][0], bv[n][0], accV[m + 4][n]);
                accV[m + 4][n] = MFMA(af1[m][1], bv[n][1], accV[m + 4][n]);
            }
        __builtin_amdgcn_s_setprio(0);

        cur ^= 1;
    }

    // ---- epilogue: bias, rotary, cos*cos, reduce over rows, atomicAdd
    const int batch = row0 >> 12;
    const int sb    = (row0 & 4095) + wr * 128 + hi * 4;

    #pragma unroll
    for (int n = 0; n < 2; ++n) {
        const int c     = n0 + wc * 32 + n * 16 + lr;   // channel in [0,2048)
        const float bK  = bias[c];
        const float bV  = bias[c + 2048];
        const bool rot  = (c < 1024);
        const float invf = exp2f((float)(c >> 1) * NEG_L2K);
        const float sgn  = (c & 1) ? 1.0f : -1.0f;
        float colsum = 0.0f;
        #pragma unroll
        for (int m = 0; m < 8; ++m) {
            const int srow = sb + m * 16;
            #pragma unroll
            for (int q = 0; q < 4; ++q) {
                float kv = accK[m][n][q] + bK;
                float vv = accV[m][n][q] + bV;
                float pk = __shfl_xor(kv, 1);
                float pv = __shfl_xor(vv, 1);
                float kr = kv, vr = vv;
                if (rot) {
                    float sn, cs;
                    __sincosf((float)(srow + q) * invf, &sn, &cs);
                    float tt = sgn * sn;
                    kr = kv * cs + pk * tt;
                    vr = vv * cs + pv * tt;
                }
                colsum += __cosf(kr) * __cosf(vr);
            }
        }
        colsum += __shfl_xor(colsum, 16);
        colsum += __shfl_xor(colsum, 32);
        if (lane < 16)
            atomicAdd(&A[batch * 2048 + c], colsum);
    }
}

// ---------------- Kernel 4: out = (0.5*A + 0.5) * X --------------------
__global__ void scale_out_kernel(const float* __restrict__ X,
                                 const float* __restrict__ A,
                                 float* __restrict__ out, int n4) {
    int gid = blockIdx.x * blockDim.x + threadIdx.x;
    int stride = gridDim.x * blockDim.x;
    for (int i = gid; i < n4; i += stride) {
        int e0 = i * 4;
        int b  = e0 >> 23;        // S*D = 2^23
        int d  = e0 & 2047;
        float4 a4 = *(const float4*)(A + b * 2048 + d);
        float4 x4 = ((const float4*)X)[i];
        float4 o;
        o.x = (0.5f * a4.x + 0.5f) * x4.x;
        o.y = (0.5f * a4.y + 0.5f) * x4.y;
        o.z = (0.5f * a4.z + 0.5f) * x4.z;
        o.w = (0.5f * a4.w + 0.5f) * x4.w;
        ((float4*)out)[i] = o;
    }
}

extern "C" void kernel_launch(void* const* d_in, const int* in_sizes, int n_in,
                              void* d_out, int out_size, void* d_ws, size_t ws_size,
                              hipStream_t stream) {
    const float* X    = (const float*)d_in[0];   // [4][4096][2048]
    const float* W    = (const float*)d_in[1];   // [2048][4096]
    const float* bias = (const float*)d_in[2];   // [4096]
    float* out = (float*)d_out;

    const size_t szA  = 32768;                       // 4*2048*4 (padded)
    const size_t szWt = (size_t)4096 * 2048 * 2;     // 16.8 MB
    const size_t szXb = (size_t)16384 * 2048 * 2;    // 67.1 MB

    char* ws = (char*)d_ws;
    float* A = (float*)ws;                           // assume ws >= 32 KB
    unsigned short* Wt;
    unsigned short* Xb;
    if (ws_size >= szA + szWt + szXb) {
        Wt = (unsigned short*)(ws + szA);
        Xb = (unsigned short*)(ws + szA + szWt);
    } else if (ws_size >= szA + szWt) {
        Wt = (unsigned short*)(ws + szA);
        Xb = (unsigned short*)d_out;                 // scratch; rewritten by kernel 4
    } else {
        Xb = (unsigned short*)d_out;
        Wt = (unsigned short*)((char*)d_out + szXb); // 67+16.8 MB <= 134 MB
    }

    prep_x_kernel<<<2048, 256, 0, stream>>>(X, Xb, A, 16384 * 2048 / 8);
    prep_w_kernel<<<dim3(64, 32), 256, 0, stream>>>(W, Wt);
    gemm_acos_kernel<<<1024, 512, 0, stream>>>(Xb, Wt, bias, A);
    scale_out_kernel<<<2048, 256, 0, stream>>>(X, A, out, 16384 * 2048 / 4);
}